// Round 11
// baseline (322.883 us; speedup 1.0000x reference)
//
#include <hip/hip_runtime.h>
#include <math.h>

#define BOX   256
#define NPTS  50000
#define LATD  10
#define NEUR  32
#define NLAY  3
#define BATCH 16

#define MTPB  256
#define MPPT  3
#define MPTS  (MTPB*MPPT)                  // 768 points per mlp block
#define MBLKX ((NPTS + MPTS - 1)/MPTS)     // 66

#define PTPB  256
#define PBLKX ((NPTS + PTPB - 1)/PTPB)     // 196

#define CELLS_X 64                          // 4x4-px cells
#define CELLS   (CELLS_X*CELLS_X)           // 4096
#define PREF_STRIDE 4104
#define CHUNK   256
#define WCAP    4608

#define IMG_ELEMS (BATCH*BOX*BOX)
#define OFF_IMG2  (IMG_ELEMS)
#define OFF_PROJ  (2*IMG_ELEMS)
#define OFF_POS   (OFF_PROJ + BATCH*NPTS*2)
#define OFF_RES   (OFF_POS  + BATCH*NPTS*3)

// ws ints: counts[16*4096] | n_work[16] | prefix[16*4104] | work[16*4608] | aux[16*50000]
// then (16B aligned): recs float4[16*50000]   -> ~16.8 MB total
#define WS_COUNTS 0
#define WS_NWORK  (BATCH*CELLS)
#define WS_PREFIX (WS_NWORK + BATCH)
#define WS_WORK   (WS_PREFIX + BATCH*PREF_STRIDE)
#define WS_AUX    (WS_WORK + BATCH*WCAP)
#define WS_INTS   (WS_AUX + BATCH*NPTS)

__device__ __forceinline__ float fast_tanh(float x) {
    return 1.0f - 2.0f / (__expf(2.0f * x) + 1.0f);
}

// ---- kernel A: fused MLP (3 pts/thread) + outputs + histogram + base claim ----
__global__ __launch_bounds__(MTPB) void mlp_bin(
    const float* __restrict__ z, const float* __restrict__ r,
    const float* __restrict__ pos_param, const float* __restrict__ amp,
    const float* __restrict__ lin0_w, const float* __restrict__ deform_w,
    const float* __restrict__ deform_b, const float* __restrict__ lin1a_w,
    const float* __restrict__ lin1b_w, const float* __restrict__ linamp_w,
    const float* __restrict__ linamp_b, const int* __restrict__ dflag,
    float* __restrict__ out, int* __restrict__ counts, int* __restrict__ aux)
{
    __shared__ float s_zpart[NEUR];
    __shared__ int   s_cnt[CELLS];          // 16 KB histogram -> then bases
    const int b = blockIdx.y, tid = threadIdx.x;

    for (int i = tid; i < CELLS; i += MTPB) s_cnt[i] = 0;
    if (tid < NEUR) {
        float acc = 0.f;
        #pragma unroll
        for (int j = 0; j < LATD-1; j++)
            acc = fmaf(lin0_w[tid*12 + 3 + j], z[b*LATD + j], acc);
        s_zpart[tid] = acc;
    }
    __syncthreads();

    const int n0 = blockIdx.x*MPTS + tid;
    const int n1 = n0 + MTPB;
    const int n2 = n0 + 2*MTPB;
    const bool v0 = (n0 < NPTS), v1 = (n1 < NPTS), v2 = (n2 < NPTS);
    const int m0 = v0 ? n0 : 0, m1 = v1 ? n1 : 0, m2 = v2 ? n2 : 0;
    const int dd = *dflag;

    const float r00 = r[b*9+0], r01 = r[b*9+1];
    const float r10 = r[b*9+3], r11 = r[b*9+4];
    const float r20 = r[b*9+6], r21 = r[b*9+7];

    const float p00 = pos_param[m0*3+0], p01 = pos_param[m0*3+1], p02 = pos_param[m0*3+2];
    const float p10 = pos_param[m1*3+0], p11 = pos_param[m1*3+1], p12 = pos_param[m1*3+2];
    const float p20 = pos_param[m2*3+0], p21 = pos_param[m2*3+1], p22 = pos_param[m2*3+2];

    float res00=0.f,res01=0.f,res02=0.f, res10=0.f,res11=0.f,res12=0.f,
          res20=0.f,res21=0.f,res22=0.f;
    if (dd > 0) {
        float h0[NEUR], h1[NEUR], h2[NEUR];
        #pragma unroll
        for (int o = 0; o < NEUR; o++) {
            const float w0 = lin0_w[o*12+0], w1 = lin0_w[o*12+1], w2 = lin0_w[o*12+2];
            const float zp = s_zpart[o];
            h0[o] = fmaf(w0,p00, fmaf(w1,p01, fmaf(w2,p02, zp)));
            h1[o] = fmaf(w0,p10, fmaf(w1,p11, fmaf(w2,p12, zp)));
            h2[o] = fmaf(w0,p20, fmaf(w1,p21, fmaf(w2,p22, zp)));
        }
        #pragma unroll 1
        for (int l = 0; l < NLAY; l++) {
            const float* __restrict__ W  = deform_w + l*NEUR*NEUR;
            const float* __restrict__ bb = deform_b + l*NEUR;
            float g0[NEUR], g1[NEUR], g2[NEUR];
            #pragma unroll
            for (int o = 0; o < NEUR; o++) {
                float a0 = bb[o], a1 = a0, a2 = a0;
                #pragma unroll
                for (int j = 0; j < NEUR; j++) {
                    const float w = W[o*NEUR + j];
                    a0 = fmaf(w, h0[j], a0);
                    a1 = fmaf(w, h1[j], a1);
                    a2 = fmaf(w, h2[j], a2);
                }
                g0[o] = fmaxf(a0, 0.f) + h0[o];
                g1[o] = fmaxf(a1, 0.f) + h1[o];
                g2[o] = fmaxf(a2, 0.f) + h2[o];
            }
            #pragma unroll
            for (int o = 0; o < NEUR; o++) { h0[o]=g0[o]; h1[o]=g1[o]; h2[o]=g2[o]; }
        }
        float t00=0.f,t01=0.f,t02=0.f, t10=0.f,t11=0.f,t12=0.f, t20=0.f,t21=0.f,t22=0.f;
        #pragma unroll
        for (int j = 0; j < NEUR; j++) {
            const float wa = lin1a_w[0*NEUR+j], wb = lin1a_w[1*NEUR+j], wc = lin1a_w[2*NEUR+j];
            t00 = fmaf(wa, h0[j], t00);  t10 = fmaf(wa, h1[j], t10);  t20 = fmaf(wa, h2[j], t20);
            t01 = fmaf(wb, h0[j], t01);  t11 = fmaf(wb, h1[j], t11);  t21 = fmaf(wb, h2[j], t21);
            t02 = fmaf(wc, h0[j], t02);  t12 = fmaf(wc, h1[j], t12);  t22 = fmaf(wc, h2[j], t22);
        }
        t00 = fast_tanh(t00); t01 = fast_tanh(t01); t02 = fast_tanh(t02);
        t10 = fast_tanh(t10); t11 = fast_tanh(t11); t12 = fast_tanh(t12);
        t20 = fast_tanh(t20); t21 = fast_tanh(t21); t22 = fast_tanh(t22);
        res00 = fmaf(t00, lin1b_w[0], fmaf(t01, lin1b_w[1], t02*lin1b_w[2]));
        res01 = fmaf(t00, lin1b_w[3], fmaf(t01, lin1b_w[4], t02*lin1b_w[5]));
        res02 = fmaf(t00, lin1b_w[6], fmaf(t01, lin1b_w[7], t02*lin1b_w[8]));
        res10 = fmaf(t10, lin1b_w[0], fmaf(t11, lin1b_w[1], t12*lin1b_w[2]));
        res11 = fmaf(t10, lin1b_w[3], fmaf(t11, lin1b_w[4], t12*lin1b_w[5]));
        res12 = fmaf(t10, lin1b_w[6], fmaf(t11, lin1b_w[7], t12*lin1b_w[8]));
        res20 = fmaf(t20, lin1b_w[0], fmaf(t21, lin1b_w[1], t22*lin1b_w[2]));
        res21 = fmaf(t20, lin1b_w[3], fmaf(t21, lin1b_w[4], t22*lin1b_w[5]));
        res22 = fmaf(t20, lin1b_w[6], fmaf(t21, lin1b_w[7], t22*lin1b_w[8]));
    }

    int cell0=0, cell1=0, cell2=0, rank0=0, rank1=0, rank2=0;

    #define EPILOGUE(vN, nN, rA, rB, rC, cellN, rankN)                                   \
    if (vN) {                                                                            \
        const float pos0 = p##nN##0 + rA, pos1 = p##nN##1 + rB, pos2 = p##nN##2 + rC;    \
        const float pj0 = fmaf(pos0, r00, fmaf(pos1, r10, pos2*r20));                    \
        const float pj1 = fmaf(pos0, r01, fmaf(pos1, r11, pos2*r21));                    \
        const long long bn = (long long)b*NPTS + n##nN;                                  \
        out[OFF_PROJ + bn*2 + 0] = pj0;  out[OFF_PROJ + bn*2 + 1] = pj1;                 \
        out[OFF_POS  + bn*3 + 0] = pos0; out[OFF_POS  + bn*3 + 1] = pos1;                \
        out[OFF_POS  + bn*3 + 2] = pos2;                                                 \
        out[OFF_RES  + bn*3 + 0] = rA; out[OFF_RES + bn*3 + 1] = rB;                     \
        out[OFF_RES  + bn*3 + 2] = rC;                                                   \
        const float px0 = (pj0 + 0.5f) * (float)(BOX-1);                                 \
        const float px1 = (pj1 + 0.5f) * (float)(BOX-1);                                 \
        const int c0 = (int)fminf(fmaxf(floorf(px0 + 0.5f), 0.f), 255.f);                \
        const int c1 = (int)fminf(fmaxf(floorf(px1 + 0.5f), 0.f), 255.f);                \
        cellN = (c0>>2)*CELLS_X + (c1>>2);                                               \
        rankN = atomicAdd(&s_cnt[cellN], 1);                                             \
    }

    EPILOGUE(v0, 0, res00, res01, res02, cell0, rank0)
    EPILOGUE(v1, 1, res10, res11, res12, cell1, rank1)
    EPILOGUE(v2, 2, res20, res21, res22, cell2, rank2)
    #undef EPILOGUE

    __syncthreads();
    for (int c = tid; c < CELLS; c += MTPB) {
        const int cnt = s_cnt[c];
        if (cnt > 0) s_cnt[c] = atomicAdd(&counts[b*CELLS + c], cnt);
    }
    __syncthreads();
    if (v0) aux[b*NPTS + n0] = (cell0 << 16) | (s_cnt[cell0] + rank0);
    if (v1) aux[b*NPTS + n1] = (cell1 << 16) | (s_cnt[cell1] + rank1);
    if (v2) aux[b*NPTS + n2] = (cell2 << 16) | (s_cnt[cell2] + rank2);
}

// ------- kernel B: prefix scan of 4096 cells per image + fused work-item build -------
__global__ __launch_bounds__(1024) void scan_cells(
    const int* __restrict__ counts, int* __restrict__ prefix,
    int* __restrict__ n_work, int* __restrict__ work)
{
    __shared__ int lds[1024];
    __shared__ int s_nw;
    const int img = blockIdx.x, t = threadIdx.x;
    if (t == 0) s_nw = 0;
    const int4 v = ((const int4*)(counts + img*CELLS))[t];
    const int s0 = v.x, s1 = s0 + v.y, s2 = s1 + v.z, s3 = s2 + v.w;
    lds[t] = s3;
    __syncthreads();
    #pragma unroll 1
    for (int off = 1; off < 1024; off <<= 1) {
        const int add = (t >= off) ? lds[t - off] : 0;
        __syncthreads();
        lds[t] += add;
        __syncthreads();
    }
    const int incl = lds[t];
    const int base = incl - s3;
    ((int4*)(prefix + img*PREF_STRIDE))[t] = make_int4(base, base+s0, base+s1, base+s2);
    if (t == 1023) prefix[img*PREF_STRIDE + CELLS] = incl;

    // fused build_work: each thread owns cells 4t..4t+3 with counts v.x..v.w
    const int cnts[4] = { v.x, v.y, v.z, v.w };
    #pragma unroll
    for (int i = 0; i < 4; i++) {
        const int cnt = cnts[i];
        if (cnt > 0) {
            const int c = 4*t + i;
            const int nch = (cnt + CHUNK - 1)/CHUNK;
            const int wb = atomicAdd(&s_nw, nch);
            for (int k = 0; k < nch; k++) work[img*WCAP + wb + k] = (c << 8) | k;
        }
    }
    __syncthreads();
    if (t == 0) n_work[img] = s_nw;
}

// ------- kernel C: place records at final cell-sorted positions -------
__global__ __launch_bounds__(PTPB) void place(
    const float* __restrict__ z, const float* __restrict__ amp,
    const float* __restrict__ linamp_w, const float* __restrict__ linamp_b,
    const float* __restrict__ out, const int* __restrict__ prefix,
    const int* __restrict__ aux, float4* __restrict__ recs)
{
    const int b = blockIdx.y;
    const int n = blockIdx.x*PTPB + threadIdx.x;
    if (n >= NPTS) return;

    const long long bn = (long long)b*NPTS + n;
    const float pj0 = out[OFF_PROJ + bn*2 + 0];
    const float pj1 = out[OFF_PROJ + bn*2 + 1];
    const float lo = fmaf(z[b*LATD + LATD-1], linamp_w[n], linamp_b[n]);
    const float a  = amp[0] / (1.0f + __expf(-lo));
    const float px0 = (pj0 + 0.5f) * (float)(BOX-1);
    const float px1 = (pj1 + 0.5f) * (float)(BOX-1);

    const int av  = aux[b*NPTS + n];
    const int cell = av >> 16, wr = av & 0xFFFF;
    const int dst  = prefix[b*PREF_STRIDE + cell] + wr;
    recs[(long long)b*NPTS + dst] = make_float4(px0, px1, a, 0.f);
}

// -------- kernel D: one wave per chunk; scalar record loads; 2-exp + int masks --------
__global__ __launch_bounds__(256) void gather_work(
    const float4* __restrict__ recs, const int* __restrict__ prefix,
    const int* __restrict__ n_work, const int* __restrict__ work,
    float* __restrict__ out)
{
    const int b    = blockIdx.y;
    const int wave = blockIdx.x*4 + (threadIdx.x >> 6);   // 0..255
    const int lane = threadIdx.x & 63;
    const int nw   = n_work[b];

    const int* __restrict__ P = prefix + b*PREF_STRIDE;
    const float4* __restrict__ R = recs + (long long)b*NPTS;
    float* __restrict__ img = out + (size_t)b*BOX*BOX;
    const float Kc  = -0.32059884f;                // -log2(e)/(2*sig^2)
    const float K8  = 8.0f  * Kc;
    const float K16 = 16.0f * Kc;
    const float C32 = 0.00081582472f;              // 2^(32*Kc)

    for (int it = wave; it < nw; it += 256) {
        const int wd   = __builtin_amdgcn_readfirstlane(work[b*WCAP + it]);
        const int cell = wd >> 8, kch = wd & 255;
        const int s = P[cell] + kch*CHUNK;          // scalar (cell uniform)
        const int e = min(P[cell+1], s + CHUNK);

        const int cy = cell >> 6, cx = cell & 63;
        const int col = lane & 15, r0 = lane >> 4;
        const int gx  = 4*cx - 4 + col;
        const int gy0 = 4*cy - 4 + r0;
        const float xf  = (float)gx;
        const float y0f = (float)gy0;
        const float fr0 = (float)r0;
        const float cy4 = (float)(4*cy);

        float a0 = 0.f, a1 = 0.f, a2 = 0.f;
        #pragma unroll 4
        for (int rr = s; rr < e; ++rr) {
            const float4 rc = R[rr];                // uniform addr -> s_load_dwordx4
            const float ry = rc.x, rx = rc.y, ra = rc.z;

            const float dx = xf - rx;
            float aex = ra * exp2f((dx*dx)*Kc);
            aex = (dx > -4.5f && dx <= 4.5f) ? aex : 0.f;

            const float dy = y0f - ry;
            const float e0 = exp2f((dy*dy)*Kc);
            const float u  = exp2f(fmaf(dy, K8, K16));
            const float e1 = e0 * u;
            const float e2 = e1 * (u * C32);
            const float st = floorf(ry + 0.5f) - cy4;
            const float w0 = (fr0 >= st) ? e0 : 0.f;
            const float w2 = (fr0 <= st) ? e2 : 0.f;
            a0 = fmaf(w0, aex, a0);
            a1 = fmaf(e1, aex, a1);
            a2 = fmaf(w2, aex, a2);
        }

        if (gx >= 0 && gx < BOX) {
            if (a0 != 0.f && gy0 >= 0)      atomicAdd(&img[ gy0     *BOX + gx], a0);
            if (a1 != 0.f)                  atomicAdd(&img[(gy0 + 4)*BOX + gx], a1);
            if (a2 != 0.f && gy0 + 8 < BOX) atomicAdd(&img[(gy0 + 8)*BOX + gx], a2);
        }
    }
}

__global__ __launch_bounds__(256) void copy_img(const float4* __restrict__ src,
                                                float4* __restrict__ dst, int n4)
{
    int i = blockIdx.x*blockDim.x + threadIdx.x;
    if (i < n4) dst[i] = src[i];
}

extern "C" void kernel_launch(void* const* d_in, const int* in_sizes, int n_in,
                              void* d_out, int out_size, void* d_ws, size_t ws_size,
                              hipStream_t stream)
{
    const float* z        = (const float*)d_in[0];
    const float* r        = (const float*)d_in[1];
    const float* posp     = (const float*)d_in[2];
    const float* amp      = (const float*)d_in[3];
    const float* lin0_w   = (const float*)d_in[4];
    const float* deform_w = (const float*)d_in[5];
    const float* deform_b = (const float*)d_in[6];
    const float* lin1a_w  = (const float*)d_in[7];
    const float* lin1b_w  = (const float*)d_in[8];
    const float* linamp_w = (const float*)d_in[9];
    const float* linamp_b = (const float*)d_in[10];
    const int*   dflag    = (const int*)d_in[11];
    float* out = (float*)d_out;

    int* ws_i    = (int*)d_ws;
    int* counts  = ws_i + WS_COUNTS;
    int* n_work  = ws_i + WS_NWORK;
    int* prefix  = ws_i + WS_PREFIX;
    int* work    = ws_i + WS_WORK;
    int* aux     = ws_i + WS_AUX;
    float4* recs = (float4*)((char*)d_ws + (size_t)WS_INTS*sizeof(int));

    hipMemsetAsync(counts, 0, (size_t)(BATCH*CELLS + BATCH)*sizeof(int), stream);
    hipMemsetAsync(out, 0, (size_t)IMG_ELEMS*sizeof(float), stream);

    dim3 gridM(MBLKX, BATCH);
    mlp_bin<<<gridM, MTPB, 0, stream>>>(z, r, posp, amp, lin0_w, deform_w, deform_b,
                                        lin1a_w, lin1b_w, linamp_w, linamp_b, dflag,
                                        out, counts, aux);

    scan_cells<<<BATCH, 1024, 0, stream>>>(counts, prefix, n_work, work);

    dim3 gridP(PBLKX, BATCH);
    place<<<gridP, PTPB, 0, stream>>>(z, amp, linamp_w, linamp_b, out, prefix, aux, recs);

    dim3 gridG(64, BATCH);
    gather_work<<<gridG, 256, 0, stream>>>(recs, prefix, n_work, work, out);

    const int n4 = IMG_ELEMS/4;
    copy_img<<<(n4 + 255)/256, 256, 0, stream>>>((const float4*)out,
                                                 (float4*)(out + OFF_IMG2), n4);
}

// Round 12
// 295.262 us; speedup vs baseline: 1.0935x; 1.0935x over previous
//
#include <hip/hip_runtime.h>
#include <math.h>

#define BOX   256
#define NPTS  50000
#define LATD  10
#define NEUR  32
#define NLAY  3
#define BATCH 16

#define MTPB  256
#define MPPT  2
#define MPTS  (MTPB*MPPT)                  // 512 points per mlp block
#define MBLKX ((NPTS + MPTS - 1)/MPTS)     // 98

#define PTPB  256
#define PBLKX ((NPTS + PTPB - 1)/PTPB)     // 196

#define CELLS_X 64                          // 4x4-px cells
#define CELLS   (CELLS_X*CELLS_X)           // 4096
#define PREF_STRIDE 4104
#define CHUNK   256
#define WCAP    4608

#define IMG_ELEMS (BATCH*BOX*BOX)
#define OFF_IMG2  (IMG_ELEMS)
#define OFF_PROJ  (2*IMG_ELEMS)
#define OFF_POS   (OFF_PROJ + BATCH*NPTS*2)
#define OFF_RES   (OFF_POS  + BATCH*NPTS*3)

// ws ints: counts[16*4096] | n_work[16] | prefix[16*4104] | work[16*4608] | aux[16*50000]
// then (16B aligned): recs float4[16*50000]   -> ~16.8 MB total
#define WS_COUNTS 0
#define WS_NWORK  (BATCH*CELLS)
#define WS_PREFIX (WS_NWORK + BATCH)
#define WS_WORK   (WS_PREFIX + BATCH*PREF_STRIDE)
#define WS_AUX    (WS_WORK + BATCH*WCAP)
#define WS_INTS   (WS_AUX + BATCH*NPTS)

__device__ __forceinline__ float fast_tanh(float x) {
    return 1.0f - 2.0f / (__expf(2.0f * x) + 1.0f);
}

// ---- kernel A: fused MLP (2 pts/thread, VGPR~88 sweet spot) + histogram + base claim ----
__global__ __launch_bounds__(MTPB) void mlp_bin(
    const float* __restrict__ z, const float* __restrict__ r,
    const float* __restrict__ pos_param, const float* __restrict__ amp,
    const float* __restrict__ lin0_w, const float* __restrict__ deform_w,
    const float* __restrict__ deform_b, const float* __restrict__ lin1a_w,
    const float* __restrict__ lin1b_w, const float* __restrict__ linamp_w,
    const float* __restrict__ linamp_b, const int* __restrict__ dflag,
    float* __restrict__ out, int* __restrict__ counts, int* __restrict__ aux)
{
    __shared__ float s_zpart[NEUR];
    __shared__ int   s_cnt[CELLS];          // 16 KB histogram -> then bases
    const int b = blockIdx.y, tid = threadIdx.x;

    for (int i = tid; i < CELLS; i += MTPB) s_cnt[i] = 0;
    if (tid < NEUR) {
        float acc = 0.f;
        #pragma unroll
        for (int j = 0; j < LATD-1; j++)
            acc = fmaf(lin0_w[tid*12 + 3 + j], z[b*LATD + j], acc);
        s_zpart[tid] = acc;
    }
    __syncthreads();

    const int n0 = blockIdx.x*MPTS + tid;
    const int n1 = n0 + MTPB;
    const bool v0 = (n0 < NPTS), v1 = (n1 < NPTS);
    const int m0 = v0 ? n0 : 0, m1 = v1 ? n1 : 0;
    const int dd = *dflag;

    const float r00 = r[b*9+0], r01 = r[b*9+1];
    const float r10 = r[b*9+3], r11 = r[b*9+4];
    const float r20 = r[b*9+6], r21 = r[b*9+7];

    const float p00 = pos_param[m0*3+0], p01 = pos_param[m0*3+1], p02 = pos_param[m0*3+2];
    const float p10 = pos_param[m1*3+0], p11 = pos_param[m1*3+1], p12 = pos_param[m1*3+2];

    float res00=0.f, res01=0.f, res02=0.f, res10=0.f, res11=0.f, res12=0.f;
    if (dd > 0) {
        float h0[NEUR], h1[NEUR];
        #pragma unroll
        for (int o = 0; o < NEUR; o++) {
            const float w0 = lin0_w[o*12+0], w1 = lin0_w[o*12+1], w2 = lin0_w[o*12+2];
            const float zp = s_zpart[o];
            h0[o] = fmaf(w0,p00, fmaf(w1,p01, fmaf(w2,p02, zp)));
            h1[o] = fmaf(w0,p10, fmaf(w1,p11, fmaf(w2,p12, zp)));
        }
        #pragma unroll 1
        for (int l = 0; l < NLAY; l++) {
            const float* __restrict__ W  = deform_w + l*NEUR*NEUR;
            const float* __restrict__ bb = deform_b + l*NEUR;
            float g0[NEUR], g1[NEUR];
            #pragma unroll
            for (int o = 0; o < NEUR; o++) {
                float a0 = bb[o], a1 = a0;
                #pragma unroll
                for (int j = 0; j < NEUR; j++) {
                    const float w = W[o*NEUR + j];
                    a0 = fmaf(w, h0[j], a0);
                    a1 = fmaf(w, h1[j], a1);
                }
                g0[o] = fmaxf(a0, 0.f) + h0[o];
                g1[o] = fmaxf(a1, 0.f) + h1[o];
            }
            #pragma unroll
            for (int o = 0; o < NEUR; o++) { h0[o] = g0[o]; h1[o] = g1[o]; }
        }
        float t00=0.f,t01=0.f,t02=0.f,t10=0.f,t11=0.f,t12=0.f;
        #pragma unroll
        for (int j = 0; j < NEUR; j++) {
            const float wa = lin1a_w[0*NEUR+j], wb = lin1a_w[1*NEUR+j], wc = lin1a_w[2*NEUR+j];
            t00 = fmaf(wa, h0[j], t00);  t10 = fmaf(wa, h1[j], t10);
            t01 = fmaf(wb, h0[j], t01);  t11 = fmaf(wb, h1[j], t11);
            t02 = fmaf(wc, h0[j], t02);  t12 = fmaf(wc, h1[j], t12);
        }
        t00 = fast_tanh(t00); t01 = fast_tanh(t01); t02 = fast_tanh(t02);
        t10 = fast_tanh(t10); t11 = fast_tanh(t11); t12 = fast_tanh(t12);
        res00 = fmaf(t00, lin1b_w[0], fmaf(t01, lin1b_w[1], t02*lin1b_w[2]));
        res01 = fmaf(t00, lin1b_w[3], fmaf(t01, lin1b_w[4], t02*lin1b_w[5]));
        res02 = fmaf(t00, lin1b_w[6], fmaf(t01, lin1b_w[7], t02*lin1b_w[8]));
        res10 = fmaf(t10, lin1b_w[0], fmaf(t11, lin1b_w[1], t12*lin1b_w[2]));
        res11 = fmaf(t10, lin1b_w[3], fmaf(t11, lin1b_w[4], t12*lin1b_w[5]));
        res12 = fmaf(t10, lin1b_w[6], fmaf(t11, lin1b_w[7], t12*lin1b_w[8]));
    }

    int cell0 = 0, cell1 = 0, rank0 = 0, rank1 = 0;

    // ---- epilogue point 0 ----
    if (v0) {
        const float pos0 = p00 + res00, pos1 = p01 + res01, pos2 = p02 + res02;
        const float pj0 = fmaf(pos0, r00, fmaf(pos1, r10, pos2*r20));
        const float pj1 = fmaf(pos0, r01, fmaf(pos1, r11, pos2*r21));
        const long long bn = (long long)b*NPTS + n0;
        out[OFF_PROJ + bn*2 + 0] = pj0;  out[OFF_PROJ + bn*2 + 1] = pj1;
        out[OFF_POS  + bn*3 + 0] = pos0; out[OFF_POS  + bn*3 + 1] = pos1;
        out[OFF_POS  + bn*3 + 2] = pos2;
        out[OFF_RES  + bn*3 + 0] = res00; out[OFF_RES + bn*3 + 1] = res01;
        out[OFF_RES  + bn*3 + 2] = res02;
        const float px0 = (pj0 + 0.5f) * (float)(BOX-1);
        const float px1 = (pj1 + 0.5f) * (float)(BOX-1);
        const int c0 = (int)fminf(fmaxf(floorf(px0 + 0.5f), 0.f), 255.f);
        const int c1 = (int)fminf(fmaxf(floorf(px1 + 0.5f), 0.f), 255.f);
        cell0 = (c0>>2)*CELLS_X + (c1>>2);
        rank0 = atomicAdd(&s_cnt[cell0], 1);
    }
    // ---- epilogue point 1 ----
    if (v1) {
        const float pos0 = p10 + res10, pos1 = p11 + res11, pos2 = p12 + res12;
        const float pj0 = fmaf(pos0, r00, fmaf(pos1, r10, pos2*r20));
        const float pj1 = fmaf(pos0, r01, fmaf(pos1, r11, pos2*r21));
        const long long bn = (long long)b*NPTS + n1;
        out[OFF_PROJ + bn*2 + 0] = pj0;  out[OFF_PROJ + bn*2 + 1] = pj1;
        out[OFF_POS  + bn*3 + 0] = pos0; out[OFF_POS  + bn*3 + 1] = pos1;
        out[OFF_POS  + bn*3 + 2] = pos2;
        out[OFF_RES  + bn*3 + 0] = res10; out[OFF_RES + bn*3 + 1] = res11;
        out[OFF_RES  + bn*3 + 2] = res12;
        const float px0 = (pj0 + 0.5f) * (float)(BOX-1);
        const float px1 = (pj1 + 0.5f) * (float)(BOX-1);
        const int c0 = (int)fminf(fmaxf(floorf(px0 + 0.5f), 0.f), 255.f);
        const int c1 = (int)fminf(fmaxf(floorf(px1 + 0.5f), 0.f), 255.f);
        cell1 = (c0>>2)*CELLS_X + (c1>>2);
        rank1 = atomicAdd(&s_cnt[cell1], 1);
    }
    __syncthreads();
    // claim global bases: one atomic per non-empty cell per block; s_cnt becomes base
    for (int c = tid; c < CELLS; c += MTPB) {
        const int cnt = s_cnt[c];
        if (cnt > 0) s_cnt[c] = atomicAdd(&counts[b*CELLS + c], cnt);
    }
    __syncthreads();
    if (v0) aux[b*NPTS + n0] = (cell0 << 16) | (s_cnt[cell0] + rank0);
    if (v1) aux[b*NPTS + n1] = (cell1 << 16) | (s_cnt[cell1] + rank1);
}

// ------- kernel B: prefix scan of 4096 cells per image + fused work-item build -------
__global__ __launch_bounds__(1024) void scan_cells(
    const int* __restrict__ counts, int* __restrict__ prefix,
    int* __restrict__ n_work, int* __restrict__ work)
{
    __shared__ int lds[1024];
    __shared__ int s_nw;
    const int img = blockIdx.x, t = threadIdx.x;
    if (t == 0) s_nw = 0;
    const int4 v = ((const int4*)(counts + img*CELLS))[t];
    const int s0 = v.x, s1 = s0 + v.y, s2 = s1 + v.z, s3 = s2 + v.w;
    lds[t] = s3;
    __syncthreads();
    #pragma unroll 1
    for (int off = 1; off < 1024; off <<= 1) {
        const int add = (t >= off) ? lds[t - off] : 0;
        __syncthreads();
        lds[t] += add;
        __syncthreads();
    }
    const int incl = lds[t];
    const int base = incl - s3;
    ((int4*)(prefix + img*PREF_STRIDE))[t] = make_int4(base, base+s0, base+s1, base+s2);
    if (t == 1023) prefix[img*PREF_STRIDE + CELLS] = incl;

    // fused build_work: each thread owns cells 4t..4t+3 with counts v.x..v.w
    const int cnts[4] = { v.x, v.y, v.z, v.w };
    #pragma unroll
    for (int i = 0; i < 4; i++) {
        const int cnt = cnts[i];
        if (cnt > 0) {
            const int c = 4*t + i;
            const int nch = (cnt + CHUNK - 1)/CHUNK;
            const int wb = atomicAdd(&s_nw, nch);
            for (int k = 0; k < nch; k++) work[img*WCAP + wb + k] = (c << 8) | k;
        }
    }
    __syncthreads();
    if (t == 0) n_work[img] = s_nw;
}

// ------- kernel C: place records at final cell-sorted positions -------
__global__ __launch_bounds__(PTPB) void place(
    const float* __restrict__ z, const float* __restrict__ amp,
    const float* __restrict__ linamp_w, const float* __restrict__ linamp_b,
    const float* __restrict__ out, const int* __restrict__ prefix,
    const int* __restrict__ aux, float4* __restrict__ recs)
{
    const int b = blockIdx.y;
    const int n = blockIdx.x*PTPB + threadIdx.x;
    if (n >= NPTS) return;

    const long long bn = (long long)b*NPTS + n;
    const float pj0 = out[OFF_PROJ + bn*2 + 0];
    const float pj1 = out[OFF_PROJ + bn*2 + 1];
    const float lo = fmaf(z[b*LATD + LATD-1], linamp_w[n], linamp_b[n]);
    const float a  = amp[0] / (1.0f + __expf(-lo));
    const float px0 = (pj0 + 0.5f) * (float)(BOX-1);
    const float px1 = (pj1 + 0.5f) * (float)(BOX-1);

    const int av  = aux[b*NPTS + n];
    const int cell = av >> 16, wr = av & 0xFFFF;
    const int dst  = prefix[b*PREF_STRIDE + cell] + wr;
    recs[(long long)b*NPTS + dst] = make_float4(px0, px1, a, 0.f);
}

// -------- kernel D: one wave per chunk; scalar record loads (8-deep); 2-exp + int masks --------
__global__ __launch_bounds__(256) void gather_work(
    const float4* __restrict__ recs, const int* __restrict__ prefix,
    const int* __restrict__ n_work, const int* __restrict__ work,
    float* __restrict__ out)
{
    const int b    = blockIdx.y;
    const int wave = blockIdx.x*4 + (threadIdx.x >> 6);   // 0..255
    const int lane = threadIdx.x & 63;
    const int nw   = n_work[b];

    const int* __restrict__ P = prefix + b*PREF_STRIDE;
    const float4* __restrict__ R = recs + (long long)b*NPTS;
    float* __restrict__ img = out + (size_t)b*BOX*BOX;
    const float Kc  = -0.32059884f;                // -log2(e)/(2*sig^2)
    const float K8  = 8.0f  * Kc;
    const float K16 = 16.0f * Kc;
    const float C32 = 0.00081582472f;              // 2^(32*Kc)

    for (int it = wave; it < nw; it += 256) {
        const int wd   = __builtin_amdgcn_readfirstlane(work[b*WCAP + it]);
        const int cell = wd >> 8, kch = wd & 255;
        const int s = P[cell] + kch*CHUNK;          // scalar (cell uniform)
        const int e = min(P[cell+1], s + CHUNK);

        const int cy = cell >> 6, cx = cell & 63;
        const int col = lane & 15, r0 = lane >> 4;
        const int gx  = 4*cx - 4 + col;
        const int gy0 = 4*cy - 4 + r0;
        const float xf  = (float)gx;
        const float y0f = (float)gy0;
        const float fr0 = (float)r0;
        const float cy4 = (float)(4*cy);

        float a0 = 0.f, a1 = 0.f, a2 = 0.f;
        #pragma unroll 8
        for (int rr = s; rr < e; ++rr) {
            const float4 rc = R[rr];                // uniform addr -> s_load_dwordx4
            const float ry = rc.x, rx = rc.y, ra = rc.z;

            const float dx = xf - rx;
            float aex = ra * exp2f((dx*dx)*Kc);
            aex = (dx > -4.5f && dx <= 4.5f) ? aex : 0.f;

            const float dy = y0f - ry;
            const float e0 = exp2f((dy*dy)*Kc);
            const float u  = exp2f(fmaf(dy, K8, K16));
            const float e1 = e0 * u;
            const float e2 = e1 * (u * C32);
            const float st = floorf(ry + 0.5f) - cy4;
            const float w0 = (fr0 >= st) ? e0 : 0.f;
            const float w2 = (fr0 <= st) ? e2 : 0.f;
            a0 = fmaf(w0, aex, a0);
            a1 = fmaf(e1, aex, a1);
            a2 = fmaf(w2, aex, a2);
        }

        if (gx >= 0 && gx < BOX) {
            if (a0 != 0.f && gy0 >= 0)      atomicAdd(&img[ gy0     *BOX + gx], a0);
            if (a1 != 0.f)                  atomicAdd(&img[(gy0 + 4)*BOX + gx], a1);
            if (a2 != 0.f && gy0 + 8 < BOX) atomicAdd(&img[(gy0 + 8)*BOX + gx], a2);
        }
    }
}

__global__ __launch_bounds__(256) void copy_img(const float4* __restrict__ src,
                                                float4* __restrict__ dst, int n4)
{
    int i = blockIdx.x*blockDim.x + threadIdx.x;
    if (i < n4) dst[i] = src[i];
}

extern "C" void kernel_launch(void* const* d_in, const int* in_sizes, int n_in,
                              void* d_out, int out_size, void* d_ws, size_t ws_size,
                              hipStream_t stream)
{
    const float* z        = (const float*)d_in[0];
    const float* r        = (const float*)d_in[1];
    const float* posp     = (const float*)d_in[2];
    const float* amp      = (const float*)d_in[3];
    const float* lin0_w   = (const float*)d_in[4];
    const float* deform_w = (const float*)d_in[5];
    const float* deform_b = (const float*)d_in[6];
    const float* lin1a_w  = (const float*)d_in[7];
    const float* lin1b_w  = (const float*)d_in[8];
    const float* linamp_w = (const float*)d_in[9];
    const float* linamp_b = (const float*)d_in[10];
    const int*   dflag    = (const int*)d_in[11];
    float* out = (float*)d_out;

    int* ws_i    = (int*)d_ws;
    int* counts  = ws_i + WS_COUNTS;
    int* n_work  = ws_i + WS_NWORK;
    int* prefix  = ws_i + WS_PREFIX;
    int* work    = ws_i + WS_WORK;
    int* aux     = ws_i + WS_AUX;
    float4* recs = (float4*)((char*)d_ws + (size_t)WS_INTS*sizeof(int));

    hipMemsetAsync(counts, 0, (size_t)(BATCH*CELLS + BATCH)*sizeof(int), stream);
    hipMemsetAsync(out, 0, (size_t)IMG_ELEMS*sizeof(float), stream);

    dim3 gridM(MBLKX, BATCH);
    mlp_bin<<<gridM, MTPB, 0, stream>>>(z, r, posp, amp, lin0_w, deform_w, deform_b,
                                        lin1a_w, lin1b_w, linamp_w, linamp_b, dflag,
                                        out, counts, aux);

    scan_cells<<<BATCH, 1024, 0, stream>>>(counts, prefix, n_work, work);

    dim3 gridP(PBLKX, BATCH);
    place<<<gridP, PTPB, 0, stream>>>(z, amp, linamp_w, linamp_b, out, prefix, aux, recs);

    dim3 gridG(64, BATCH);
    gather_work<<<gridG, 256, 0, stream>>>(recs, prefix, n_work, work, out);

    const int n4 = IMG_ELEMS/4;
    copy_img<<<(n4 + 255)/256, 256, 0, stream>>>((const float4*)out,
                                                 (float4*)(out + OFF_IMG2), n4);
}